// Round 6
// baseline (115.404 us; speedup 1.0000x reference)
//
#include <hip/hip_runtime.h>

#define M 32                        // reflection coeffs
#define NC 33                       // floats per row
#define TPB 128                     // threads (rows) per tile, 2 waves
#define FPB (TPB * NC)              // 4224 floats = 16896 B per tile
#define TAIL 4096                   // float index where scalar tail begins
#define V4 8                        // float4 rounds per thread in store phase
#define NBLOCKS 1024                // 4 resident blocks/CU (LDS-limited)

typedef float f4 __attribute__((ext_vector_type(4)));

// ---- async global->LDS DMA (no VGPR round-trip) ----
__device__ __forceinline__ void dma16(const float* g, float* l) {
    __builtin_amdgcn_global_load_lds(
        (const __attribute__((address_space(1))) unsigned int*)g,
        (__attribute__((address_space(3))) unsigned int*)l, 16, 0, 0);
}
__device__ __forceinline__ void dma4(const float* g, float* l) {
    __builtin_amdgcn_global_load_lds(
        (const __attribute__((address_space(1))) unsigned int*)g,
        (__attribute__((address_space(3))) unsigned int*)l, 4, 0, 0);
}

// Issue one full tile's DMA into lbuf: 9 vmem ops per wave.
// HW writes lds_base + lane*width; LDS layout stays linear.
__device__ __forceinline__ void issue_tile_dma(const float* __restrict__ src,
                                               float* __restrict__ lbuf,
                                               int w, int lane) {
#pragma unroll
    for (int k = 0; k < 8; ++k) {
        int fi = w * 2048 + k * 256 + lane * 4;     // matches lane*16B
        dma16(src + fi, lbuf + w * 2048 + k * 256);
    }
    int ft = TAIL + w * 64 + lane;                  // 128-float tail, width 4
    dma4(src + ft, lbuf + TAIL + w * 64);
}

// Levinson step-down for one row staged at lds[rb .. rb+32].
__device__ __forceinline__ void levinson(float* __restrict__ lds, int rb) {
    float ar[M];
#pragma unroll
    for (int j = 0; j < M; ++j) ar[j] = lds[rb + 1 + j];   // GAMMA == 1.0
#pragma unroll
    for (int m = M - 1; m >= 1; --m) {
        float km = ar[m];
        lds[rb + m + 1] = km;
        float z = 1.0f - km * km;
        float r = 1.0f / z;          // exact IEEE div — numerics-critical (R2 lesson)
        const int h = m >> 1;
#pragma unroll
        for (int j = 0; j < h; ++j) {
            float x = ar[j], y = ar[m - 1 - j];
            ar[j]         = (x - km * y) * r;
            ar[m - 1 - j] = (y - km * x) * r;
        }
        if (m & 1) ar[h] = (ar[h] - km * ar[h]) * r;
    }
    lds[rb + 1] = ar[0];
}

__device__ __forceinline__ void store_tile_nt(float* __restrict__ dst,
                                              const float* __restrict__ lds, int t) {
    const f4* l4 = (const f4*)lds;
#pragma unroll
    for (int k = 0; k < V4; ++k) {
        f4 v = l4[t + k * TPB];
        __builtin_nontemporal_store(v, (f4*)dst + t + k * TPB);
    }
    __builtin_nontemporal_store(lds[TAIL + t], dst + TAIL + t);
}

// guarded slow path for a (possibly partial) tile
__device__ __forceinline__ void process_tile_guarded(float* __restrict__ lds,
                                                     const float* __restrict__ a,
                                                     float* __restrict__ out,
                                                     long long base, long long limit, int t) {
    for (int k = 0; k < NC; ++k) {
        int g = t + k * TPB;
        long long ga = base + g;
        lds[g] = (ga < limit) ? a[ga] : 0.0f;
    }
    __syncthreads();
    levinson(lds, t * NC);
    __syncthreads();
    for (int k = 0; k < NC; ++k) {
        int g = t + k * TPB;
        long long ga = base + g;
        if (ga < limit) out[ga] = lds[g];
    }
    __syncthreads();
}

__global__ __launch_bounds__(TPB)
void lpc_to_parcor_kernel(const float* __restrict__ a,
                          float* __restrict__ out,
                          long long nrows, long long tiles_per_block) {
    __shared__ float lds[2 * FPB];                  // double buffer, 33792 B
    const int t = threadIdx.x;
    const int w = t >> 6, lane = t & 63;
    const long long limit = nrows * NC;
    const long long ntiles = (nrows + TPB - 1) / TPB;
    const long long nfull  = nrows / TPB;

    long long t0 = (long long)blockIdx.x * tiles_per_block;
    long long t1 = t0 + tiles_per_block; if (t1 > ntiles) t1 = ntiles;
    if (t0 >= t1) return;
    long long fend = (t1 < nfull) ? t1 : nfull;     // full tiles in [t0, fend)

    if (t0 < fend) {
        issue_tile_dma(a + t0 * FPB, lds, w, lane); // prologue -> buf0

        for (long long ti = t0; ti < fend; ++ti) {
            float* cur = lds + ((int)((ti - t0) & 1)) * FPB;
            float* nxt = lds + ((int)((ti - t0 + 1) & 1)) * FPB;
            const bool has_next = (ti + 1 < fend);

            // issue next tile's DMA first; it stays in flight across the
            // barriers below (raw s_barrier, never vmcnt(0) in steady state)
            if (has_next) issue_tile_dma(a + (ti + 1) * FPB, nxt, w, lane);

            // drain exactly DMA(cur): queue oldest->newest is
            //   [DMA(cur) 9][stores(prev) 9][DMA(next) 9]
            if (ti == t0) {
                if (has_next) asm volatile("s_waitcnt vmcnt(9)" ::: "memory");
                else          asm volatile("s_waitcnt vmcnt(0)" ::: "memory");
            } else {
                if (has_next) asm volatile("s_waitcnt vmcnt(18)" ::: "memory");
                else          asm volatile("s_waitcnt vmcnt(9)" ::: "memory");
            }
            __builtin_amdgcn_s_barrier();           // cur visible to all waves

            levinson(cur, t * NC);

            asm volatile("s_waitcnt lgkmcnt(0)" ::: "memory");
            __builtin_amdgcn_s_barrier();           // levinson writes visible

            store_tile_nt(out + ti * FPB, cur, t);

            asm volatile("s_waitcnt lgkmcnt(0)" ::: "memory");
            __builtin_amdgcn_s_barrier();           // cur's ds_reads done ->
                                                    // safe to DMA into it next iter
        }
    }
    // guarded tail tiles (empty for 2048*1024 rows; kept for generality)
    for (long long ti = (t0 > nfull ? t0 : nfull); ti < t1; ++ti) {
        __syncthreads();
        process_tile_guarded(lds, a, out, ti * FPB, limit, t);
    }
}

extern "C" void kernel_launch(void* const* d_in, const int* in_sizes, int n_in,
                              void* d_out, int out_size, void* d_ws, size_t ws_size,
                              hipStream_t stream) {
    const float* a = (const float*)d_in[0];
    float* out = (float*)d_out;
    long long nrows = (long long)in_sizes[0] / NC;
    long long ntiles = (nrows + TPB - 1) / TPB;
    long long blocks = (ntiles < NBLOCKS) ? ntiles : NBLOCKS;
    long long tpb_tiles = (ntiles + blocks - 1) / blocks;
    lpc_to_parcor_kernel<<<(int)blocks, TPB, 0, stream>>>(a, out, nrows, tpb_tiles);
}

// Round 7
// 93.835 us; speedup vs baseline: 1.2299x; 1.2299x over previous
//
#include <hip/hip_runtime.h>

#define M 32                        // reflection coeffs
#define NC 33                       // floats per row
#define TPB 64                      // ONE wave per block
#define ROWS 128                    // rows per tile (2 per thread)
#define FPB (ROWS * NC)             // 4224 floats = 16896 B
#define V4R 16                      // float4 staging rounds: 16*64*4 = 4096 floats
#define TAILF 4096                  // last 128 floats staged as float2 (2/thread)

typedef float f4 __attribute__((ext_vector_type(4)));
typedef float f2 __attribute__((ext_vector_type(2)));

__global__ __launch_bounds__(TPB, 2)
void lpc_to_parcor_kernel(const float* __restrict__ a,
                          float* __restrict__ out,
                          long long nrows) {
    __shared__ float lds[FPB];
    const int t = threadIdx.x;
    const long long base = (long long)blockIdx.x * FPB;   // tile start (floats)
    const long long limit = nrows * NC;
    const bool full = (base + FPB) <= limit;

    // ---- stage tile -> LDS (coalesced; contiguous b128 = conflict-free) ----
    if (full) {
        const f4* g4 = (const f4*)(a + base);
        f4* l4 = (f4*)lds;
#pragma unroll
        for (int k = 0; k < V4R; ++k)
            l4[t + k * TPB] = g4[t + k * TPB];
        ((f2*)(lds + TAILF))[t] = ((const f2*)(a + base + TAILF))[t];
    } else {
        for (int k = 0; k < 66; ++k) {           // 66*64 == FPB exactly
            int g = t + k * TPB;
            long long ga = base + g;
            lds[g] = (ga < limit) ? a[ga] : 0.0f;
        }
    }
    __syncthreads();

    // ---- packed Levinson: thread t owns rows 2t (.x) and 2t+1 (.y) ----
    // Per-component math identical to the verified scalar recipe (R2 lesson:
    // exact IEEE div only).
    const int rb = t * (2 * NC);                 // = 66*t, this thread's region
    f2 ar[M];
#pragma unroll
    for (int j = 0; j < M; ++j) {
        ar[j].x = lds[rb + 1 + j];
        ar[j].y = lds[rb + NC + 1 + j];
    }
#pragma unroll
    for (int m = M - 1; m >= 1; --m) {
        f2 km = ar[m];
        lds[rb + m + 1]      = km.x;             // out[..., m+1] row 2t
        lds[rb + NC + m + 1] = km.y;             // out[..., m+1] row 2t+1
        f2 z = 1.0f - km * km;
        f2 r;
        r.x = 1.0f / z.x;                        // exact IEEE div, 2 indep chains
        r.y = 1.0f / z.y;
        const int h = m >> 1;
#pragma unroll
        for (int j = 0; j < h; ++j) {            // packed symmetric pair update
            f2 x = ar[j], y = ar[m - 1 - j];
            ar[j]         = (x - km * y) * r;
            ar[m - 1 - j] = (y - km * x) * r;
        }
        if (m & 1) ar[h] = (ar[h] - km * ar[h]) * r;
    }
    lds[rb + 1]      = ar[0].x;
    lds[rb + NC + 1] = ar[0].y;
    // lds[rb + 0] / lds[rb + NC] still hold K for both rows.
    __syncthreads();

    // ---- store (coalesced, nontemporal) ----
    if (full) {
        const f4* l4 = (const f4*)lds;
#pragma unroll
        for (int k = 0; k < V4R; ++k) {
            f4 v = l4[t + k * TPB];
            __builtin_nontemporal_store(v, (f4*)(out + base) + t + k * TPB);
        }
        f2 v2 = ((const f2*)(lds + TAILF))[t];
        __builtin_nontemporal_store(v2, (f2*)(out + base + TAILF) + t);
    } else {
        for (int k = 0; k < 66; ++k) {
            int g = t + k * TPB;
            long long ga = base + g;
            if (ga < limit) out[ga] = lds[g];
        }
    }
}

extern "C" void kernel_launch(void* const* d_in, const int* in_sizes, int n_in,
                              void* d_out, int out_size, void* d_ws, size_t ws_size,
                              hipStream_t stream) {
    const float* a = (const float*)d_in[0];
    float* out = (float*)d_out;
    long long nrows = (long long)in_sizes[0] / NC;
    long long ntiles = (nrows + ROWS - 1) / ROWS;
    lpc_to_parcor_kernel<<<(int)ntiles, TPB, 0, stream>>>(a, out, nrows);
}